// Round 2
// baseline (305.890 us; speedup 1.0000x reference)
//
#include <hip/hip_runtime.h>

// Problem constants
constexpr int B = 16;
constexpr int S = 1024;
constexpr int DM = 512;        // D_MODEL
constexpr int H = 6;           // HEADS
constexpr int DK = 8;          // D_K == D_V
constexpr int NJ = H * DK;     // 48 projection cols per matrix
constexpr int BS = B * S;      // 16384 rows
constexpr int WB_ELEMS = 16 * NJ * 32;  // 24576 ushorts per matrix (B-frag order)

typedef __attribute__((ext_vector_type(8))) short bf16x8;
typedef __attribute__((ext_vector_type(8))) _Float16 half8;
typedef __attribute__((ext_vector_type(4))) _Float16 half4;
typedef __attribute__((ext_vector_type(4))) float floatx4;

// exp2-domain: p = exp(score) = exp2(score*log2e); QSCALE folds 1/sqrt(8)*log2e
#define LOG2E 1.4426950408889634f
#define QSCALE (0.35355339059327373f * LOG2E)

__device__ inline ushort f2bf(float f) {
  unsigned int u = __builtin_bit_cast(unsigned int, f);
  return (ushort)((u + 0x7FFFu + ((u >> 16) & 1u)) >> 16);
}

// ---------------------------------------------------------------------------
// K0: mask int32 [B,S,S] -> bitmask [B*S, 32 words] with PERMUTED bit layout:
// within each 32-key word, key k sits at bit (k&1)*16 + (k>>1), so that the
// fp16-pair mask trick ((w>>s)&0x10001)*0xFFFF covers keys (2p, 2p+1).
__global__ __launch_bounds__(256) void maskbits_kernel(
    const int* __restrict__ mask, unsigned long long* __restrict__ bits) {
  int wave = threadIdx.x >> 6, lane = threadIdx.x & 63;
  int row = blockIdx.x * 4 + wave;            // [0, B*S)
  const int* mrow = mask + (size_t)row * S;
  unsigned long long* brow = bits + (size_t)row * 16;
  // lane -> key offset within a 64-key group (two 32-key words per ballot)
  int koff = ((lane >> 5) << 5) + 2 * (lane & 15) + ((lane >> 4) & 1);
#pragma unroll
  for (int c = 0; c < 16; c++) {
    int v = mrow[c * 64 + koff];
    unsigned long long bal = __ballot(v != 0);
    if (lane == 0) brow[c] = bal;
  }
}

// ---------------------------------------------------------------------------
// K0b: blocks 0..2: W prep — fp32 [512][48] -> bf16 B-frag-ordered tiles.
// blocks 3..98: fill VB's d-slots 8..15 (d==8 -> fp16 1.0 ones row for the
// softmax denominator; d>8 -> 0) for bh = blockIdx.x-3.
__global__ __launch_bounds__(256) void wprep_kernel(
    const float* __restrict__ Wq, const float* __restrict__ Wk,
    const float* __restrict__ Wv, ushort* __restrict__ Wb,
    uint2* __restrict__ VBf) {
  int m = blockIdx.x;
  if (m < 3) {
    const float* W = (m == 0) ? Wq : (m == 1) ? Wk : Wv;
    ushort* dst = Wb + (size_t)m * WB_ELEMS;
    for (int e = threadIdx.x; e < WB_ELEMS; e += 256) {
      int kc = e / 1536;
      int rem = e - kc * 1536;
      int n = rem >> 5, kj = rem & 31;
      dst[e] = f2bf(W[(size_t)(kc * 32 + kj) * NJ + n]);
    }
  } else {
    int bh = m - 3;                       // [0, 96)
    for (int i = threadIdx.x; i < 2048; i += 256) {
      int tile = i >> 5;                  // 64 tiles of 16 keys
      int li = i & 31;
      int g = li >> 3, dd = 8 + (li & 7);
      uint hv = (dd == 8) ? 0x3C003C00u : 0u;
      uint2 val; val.x = hv; val.y = hv;
      VBf[((size_t)bh * 64 + tile) * 64 + g * 16 + dd] = val;
    }
  }
}

// ---------------------------------------------------------------------------
// K1: projections via bf16 MFMA. grid (BS/64, 3), block 256 (4 waves).
// W staged once in LDS (B-frag order); X A-frags straight from global.
// Q/K out bf16 (Q pre-scaled by QSCALE incl. log2e).
// V out fp16, written DIRECTLY in PV B-frag order (VB layout):
//   VB[bh][tile=s>>4][lane=((s>>2)&3)*16 + d][j=s&3] = fp16(V[s][d])
__global__ __launch_bounds__(256) void proj_kernel(
    const float* __restrict__ q_in, const float* __restrict__ k_in,
    const float* __restrict__ v_in, const ushort* __restrict__ Wb,
    const float* __restrict__ bq, const float* __restrict__ bk,
    const float* __restrict__ bv,
    ushort* __restrict__ Qo, ushort* __restrict__ Ko, ushort* __restrict__ Vo) {
  int m = blockIdx.y;
  const float* x    = (m == 0) ? q_in : (m == 1) ? k_in : v_in;
  const float* bias = (m == 0) ? bq   : (m == 1) ? bk   : bv;
  ushort* out       = (m == 0) ? Qo   : (m == 1) ? Ko   : Vo;
  float oscale      = (m == 0) ? QSCALE : 1.0f;
  const ushort* Wg  = Wb + (size_t)m * WB_ELEMS;

  __shared__ ushort Wl[WB_ELEMS];   // 48 KB

  int t = threadIdx.x;
  {
    const uint4* src = (const uint4*)Wg;
    uint4* dst = (uint4*)Wl;
#pragma unroll
    for (int i = 0; i < 12; i++) dst[t + i * 256] = src[t + i * 256];
  }

  int r0 = blockIdx.x * 64;
  int wave = t >> 6, lane = t & 63;
  int n16 = lane & 15, quad = lane >> 4;
  const float* xrow = x + (size_t)(r0 + wave * 16 + n16) * DM + quad * 8;

  floatx4 acc0 = {0.f, 0.f, 0.f, 0.f};
  floatx4 acc1 = {0.f, 0.f, 0.f, 0.f};
  floatx4 acc2 = {0.f, 0.f, 0.f, 0.f};

  __syncthreads();

#pragma unroll 4
  for (int kc = 0; kc < 16; kc++) {
    float4 xa = *(const float4*)(xrow + kc * 32);
    float4 xb = *(const float4*)(xrow + kc * 32 + 4);
    bf16x8 a;
    a[0] = (short)f2bf(xa.x); a[1] = (short)f2bf(xa.y);
    a[2] = (short)f2bf(xa.z); a[3] = (short)f2bf(xa.w);
    a[4] = (short)f2bf(xb.x); a[5] = (short)f2bf(xb.y);
    a[6] = (short)f2bf(xb.z); a[7] = (short)f2bf(xb.w);
    const ushort* wbase = &Wl[(kc * 48 + n16) * 32 + quad * 8];
    bf16x8 b0 = *(const bf16x8*)(wbase);
    bf16x8 b1 = *(const bf16x8*)(wbase + 16 * 32);
    bf16x8 b2 = *(const bf16x8*)(wbase + 32 * 32);
    acc0 = __builtin_amdgcn_mfma_f32_16x16x32_bf16(a, b0, acc0, 0, 0, 0);
    acc1 = __builtin_amdgcn_mfma_f32_16x16x32_bf16(a, b1, acc1, 0, 0, 0);
    acc2 = __builtin_amdgcn_mfma_f32_16x16x32_bf16(a, b2, acc2, 0, 0, 0);
  }

  // epilogue: C/D layout col=lane&15, row=quad*4+reg
  int baseR = r0 + wave * 16 + quad * 4;
#pragma unroll
  for (int j = 0; j < 3; j++) {
    floatx4 a = (j == 0) ? acc0 : (j == 1) ? acc1 : acc2;
    int n = j * 16 + n16;
    float bn = bias[n];
    int h = n >> 3, d = n & 7;
#pragma unroll
    for (int r = 0; r < 4; r++) {
      int R = baseR + r;
      int b = R >> 10, s = R & 1023;
      float fv = (a[r] + bn) * oscale;
      if (m == 2) {
        // B-frag-ordered VB write (fp16)
        size_t idx =
            ((((size_t)(b * H + h) * 64 + (s >> 4)) * 64) +
             ((s >> 2) & 3) * 16 + d) * 4 + (s & 3);
        out[idx] = __builtin_bit_cast(ushort, (_Float16)fv);
      } else {
        out[(((size_t)(b * H + h)) * S + s) * 8 + d] = f2bf(fv);
      }
    }
  }
}

// ---------------------------------------------------------------------------
// K2: MFMA attention, ZERO LDS. grid 1536 (B*H*S/64), block 256 (4 waves).
// Swapped QK^T: sc = mfma(K_tile, Q_frag) -> lane(quad,n16) holds keys
// quad*4+r for query n16. cvt_pkrtz packs those 4 keys into a half4 that IS
// the A-frag of mfma_f32_16x16x16f16 — PV consumes P straight from registers.
// V comes pre-transposed in B-frag order (VB, global, L2-hot) with a ones
// row at d=8 providing the softmax denominator.
__global__ __launch_bounds__(256, 6) void attn_kernel(
    const ushort* __restrict__ Qg, const ushort* __restrict__ Kg,
    const ushort* __restrict__ VBg /* fp16 B-frags */,
    const uint* __restrict__ bits32, float* __restrict__ A) {
  int bh = blockIdx.x >> 4;
  int qt = blockIdx.x & 15;
  int b = bh / H, h = bh % H;
  int q0 = qt * 64;

  int t = threadIdx.x;
  int wave = t >> 6, lane = t & 63;
  int quad = lane >> 4, n16 = lane & 15;

  const ushort* Kbase = Kg + (size_t)bh * S * 8;
  const uint2* VB = (const uint2*)VBg + (size_t)bh * (64 * 64);

  // Q B-frag: quad 0 holds d=0..7, other quads zero (kills padded K-range)
  bf16x8 aq = {0, 0, 0, 0, 0, 0, 0, 0};
  if (quad == 0)
    aq = *(const bf16x8*)&Qg[((size_t)bh * S + q0 + wave * 16 + n16) * 8];

  // this lane's query-row mask words (permuted bit layout)
  const uint* mrow = bits32 + (size_t)(b * S + q0 + wave * 16 + n16) * 32;

  floatx4 acc0 = {0.f, 0.f, 0.f, 0.f};
  floatx4 acc1 = {0.f, 0.f, 0.f, 0.f};
  const floatx4 zero = {0.f, 0.f, 0.f, 0.f};
  int sh0 = 2 * quad;

#pragma unroll 1
  for (int cc = 0; cc < 8; cc++) {
    uint4 mq = *(const uint4*)(mrow + cc * 4);
#pragma unroll
    for (int ci = 0; ci < 4; ci++) {
      int c = cc * 4 + ci;
      uint mw = (ci == 0) ? mq.x : (ci == 1) ? mq.y : (ci == 2) ? mq.z : mq.w;

      bf16x8 ak0 = *(const bf16x8*)&Kbase[(size_t)(c * 32 + n16) * 8];
      bf16x8 ak1 = *(const bf16x8*)&Kbase[(size_t)(c * 32 + 16 + n16) * 8];
      uint2 vb0 = VB[(2 * c) * 64 + lane];
      uint2 vb1 = VB[(2 * c + 1) * 64 + lane];

      // scores^T: C[key=quad*4+r][query=n16]
      floatx4 s0 = __builtin_amdgcn_mfma_f32_16x16x32_bf16(ak0, aq, zero, 0, 0, 0);
      floatx4 s1 = __builtin_amdgcn_mfma_f32_16x16x32_bf16(ak1, aq, zero, 0, 0, 0);

      // softmax numerators (exp2 domain), packed to fp16 pairs
      float p0 = exp2f(fminf(s0[0], 15.f)), p1 = exp2f(fminf(s0[1], 15.f));
      float p2 = exp2f(fminf(s0[2], 15.f)), p3 = exp2f(fminf(s0[3], 15.f));
      float p4 = exp2f(fminf(s1[0], 15.f)), p5 = exp2f(fminf(s1[1], 15.f));
      float p6 = exp2f(fminf(s1[2], 15.f)), p7 = exp2f(fminf(s1[3], 15.f));
      uint w0 = __builtin_bit_cast(uint, __builtin_amdgcn_cvt_pkrtz(p0, p1));
      uint w1 = __builtin_bit_cast(uint, __builtin_amdgcn_cvt_pkrtz(p2, p3));
      uint w2 = __builtin_bit_cast(uint, __builtin_amdgcn_cvt_pkrtz(p4, p5));
      uint w3 = __builtin_bit_cast(uint, __builtin_amdgcn_cvt_pkrtz(p6, p7));

      // mask -> fp16 1.0 (bit p of mw = key 2*(p&15)+(p>>4) of this tile)
      uint m0 = ((mw >> sh0) & 0x10001u) * 0xFFFFu;
      uint m1 = ((mw >> (sh0 + 1)) & 0x10001u) * 0xFFFFu;
      uint m2 = ((mw >> (sh0 + 8)) & 0x10001u) * 0xFFFFu;
      uint m3 = ((mw >> (sh0 + 9)) & 0x10001u) * 0xFFFFu;
      w0 = (m0 & 0x3C003C00u) | (~m0 & w0);
      w1 = (m1 & 0x3C003C00u) | (~m1 & w1);
      w2 = (m2 & 0x3C003C00u) | (~m2 & w2);
      w3 = (m3 & 0x3C003C00u) | (~m3 & w3);

      uint2 pu0; pu0.x = w0; pu0.y = w1;
      uint2 pu1; pu1.x = w2; pu1.y = w3;
      half4 pa0 = __builtin_bit_cast(half4, pu0);
      half4 pa1 = __builtin_bit_cast(half4, pu1);

      acc0 = __builtin_amdgcn_mfma_f32_16x16x16f16(
          pa0, __builtin_bit_cast(half4, vb0), acc0, 0, 0, 0);
      acc1 = __builtin_amdgcn_mfma_f32_16x16x16f16(
          pa1, __builtin_bit_cast(half4, vb1), acc1, 0, 0, 0);
    }
  }

  // C layout: row = query quad*4+r, col = d (n16); denominator in col 8
#pragma unroll
  for (int r = 0; r < 4; r++) {
    float sum = acc0[r] + acc1[r];
    float dnm = __shfl(sum, (lane & 48) | 8, 64);
    if (n16 < 8) {
      int qg = q0 + wave * 16 + quad * 4 + r;
      A[((size_t)(b * S + qg)) * NJ + h * 8 + n16] = sum / dnm;
    }
  }
}

// ---------------------------------------------------------------------------
// K3: out = A@Wo + bo + residual, then LayerNorm. grid BS/8, block 256.
__global__ __launch_bounds__(256) void out_ln_kernel(
    const float* __restrict__ A, const float* __restrict__ Wo,
    const float* __restrict__ bo, const float* __restrict__ qin,
    const float* __restrict__ lnw, const float* __restrict__ lnb,
    float* __restrict__ out) {
  int r0 = blockIdx.x * 8;
  int t = threadIdx.x;
  __shared__ float As[8 * NJ];
#pragma unroll
  for (int i = t; i < 8 * NJ; i += 256) As[i] = A[(size_t)r0 * NJ + i];
  __syncthreads();

  int c0 = t, c1 = t + 256;
  float acc0[8], acc1[8];
#pragma unroll
  for (int r = 0; r < 8; r++) { acc0[r] = 0.f; acc1[r] = 0.f; }

#pragma unroll 4
  for (int j = 0; j < NJ; j++) {
    float w0 = Wo[(size_t)j * DM + c0];
    float w1 = Wo[(size_t)j * DM + c1];
#pragma unroll
    for (int r = 0; r < 8; r++) {
      float a = As[r * NJ + j];
      acc0[r] += a * w0;
      acc1[r] += a * w1;
    }
  }

  float b0 = bo[c0], b1 = bo[c1];
  float y0[8], y1[8], ssum[8], sq[8];
#pragma unroll
  for (int r = 0; r < 8; r++) {
    y0[r] = acc0[r] + b0 + qin[(size_t)(r0 + r) * DM + c0];
    y1[r] = acc1[r] + b1 + qin[(size_t)(r0 + r) * DM + c1];
    ssum[r] = y0[r] + y1[r];
    sq[r] = y0[r] * y0[r] + y1[r] * y1[r];
  }

  int wave = t >> 6, lane = t & 63;
  __shared__ float reds[4][8], redq[4][8];
#pragma unroll
  for (int r = 0; r < 8; r++) {
    float s = ssum[r], qq = sq[r];
#pragma unroll
    for (int off = 32; off > 0; off >>= 1) {
      s += __shfl_xor(s, off, 64);
      qq += __shfl_xor(qq, off, 64);
    }
    if (lane == 0) { reds[wave][r] = s; redq[wave][r] = qq; }
  }
  __syncthreads();

  float lw0 = lnw[c0], lw1 = lnw[c1], lb0 = lnb[c0], lb1 = lnb[c1];
#pragma unroll
  for (int r = 0; r < 8; r++) {
    float s = (reds[0][r] + reds[1][r]) + (reds[2][r] + reds[3][r]);
    float qq = (redq[0][r] + redq[1][r]) + (redq[2][r] + redq[3][r]);
    float mu = s * (1.f / 512.f);
    float var = qq * (1.f / 512.f) - mu * mu;
    float rstd = rsqrtf(var + 1e-5f);
    out[(size_t)(r0 + r) * DM + c0] = (y0[r] - mu) * rstd * lw0 + lb0;
    out[(size_t)(r0 + r) * DM + c1] = (y1[r] - mu) * rstd * lw1 + lb1;
  }
}

// ---------------------------------------------------------------------------
extern "C" void kernel_launch(void* const* d_in, const int* in_sizes, int n_in,
                              void* d_out, int out_size, void* d_ws,
                              size_t ws_size, hipStream_t stream) {
  const float* q_in = (const float*)d_in[0];
  const float* k_in = (const float*)d_in[1];
  const float* v_in = (const float*)d_in[2];
  const int* mask = (const int*)d_in[3];
  const float* Wq = (const float*)d_in[4];
  const float* bq = (const float*)d_in[5];
  const float* Wk = (const float*)d_in[6];
  const float* bk = (const float*)d_in[7];
  const float* Wv = (const float*)d_in[8];
  const float* bv = (const float*)d_in[9];
  const float* Wo = (const float*)d_in[10];
  const float* bo = (const float*)d_in[11];
  const float* lnw = (const float*)d_in[12];
  const float* lnb = (const float*)d_in[13];
  float* out = (float*)d_out;

  constexpr size_t QKV = (size_t)B * H * S * DK;  // 786432 elements
  ushort* base = (ushort*)d_ws;
  ushort* Qw = base;
  ushort* Kw = base + QKV;
  ushort* VBw = base + 2 * QKV;           // B-frag V: 2*QKV ushorts = 3 MB
  float* Aw = (float*)(base + 4 * QKV);   // BS*48 floats = 3 MB
  unsigned long long* bits = (unsigned long long*)(Aw + (size_t)BS * NJ);  // 2 MB
  ushort* Wb = (ushort*)(bits + (size_t)BS * 16);  // 3*24576 bf16

  maskbits_kernel<<<BS / 4, 256, 0, stream>>>(mask, bits);
  wprep_kernel<<<3 + B * H, 256, 0, stream>>>(Wq, Wk, Wv, Wb, (uint2*)VBw);
  proj_kernel<<<dim3(BS / 64, 3), 256, 0, stream>>>(
      q_in, k_in, v_in, Wb, bq, bk, bv, Qw, Kw, VBw);
  attn_kernel<<<(B * H * S) / 64, 256, 0, stream>>>(
      Qw, Kw, VBw, (const uint*)bits, Aw);
  out_ln_kernel<<<BS / 8, 256, 0, stream>>>(Aw, Wo, bo, q_in, lnw, lnb, out);
}